// Round 10
// baseline (1166.898 us; speedup 1.0000x reference)
//
#include <hip/hip_runtime.h>
#include <hip/hip_cooperative_groups.h>
#include <hip/hip_bf16.h>
#include <math.h>

namespace cg = cooperative_groups;

#define HEADS   4
#define HIDDEN  256
#define FIN     128
#define NGRAPH  256
#define WPB     4    // waves (=nodes) per agg group
#define HISTB   512  // hist blocks appended to gemm grid
#define PCHUNK  64   // nodes per pool chunk

using frag_ab = __attribute__((ext_vector_type(8))) short;   // 8 bf16 (4 VGPRs)
using frag_cd = __attribute__((ext_vector_type(4))) float;   // 4 fp32

__device__ __forceinline__ float bf2f(unsigned short u) {
  union { unsigned int i; float f; } v; v.i = ((unsigned int)u) << 16; return v.f;
}
__device__ __forceinline__ unsigned short f2bf(float f) {
  union { float f; unsigned int i; } v; v.f = f;
  unsigned int b = v.i;
  b += 0x7FFFu + ((b >> 16) & 1u);   // round-to-nearest-even
  return (unsigned short)(b >> 16);
}

// ================= kernel A: MFMA GEMM (B-frags direct from W) + edge histogram =================
__global__ __launch_bounds__(256) void k_gemmhist(
    const float* __restrict__ x, const float* __restrict__ W,
    const float* __restrict__ att_s, const float* __restrict__ att_d,
    unsigned short* __restrict__ h16, float* __restrict__ a_src, float* __restrict__ a_dst,
    const int* __restrict__ ei, int* __restrict__ count,
    int nNodes, int E, int gemmBlocks)
{
  __shared__ unsigned short As[32 * FIN];       // 8 KB, XOR-swizzled
  const int t = threadIdx.x;

  if (blockIdx.x >= gemmBlocks) {               // ---- histogram part ----
    int i = (blockIdx.x - gemmBlocks) * 256 + t;
    int stride = HISTB * 256;
    for (int e = i; e < E; e += stride) atomicAdd(&count[ei[E + e]], 1);
    return;                                     // self loops handled in scan (+1)
  }

  const int n0 = blockIdx.x * 32;

  // ---- stage x tile (fp32 -> bf16) into LDS with (row&7)<<4 byte-XOR swizzle ----
  {
    const int row = t >> 3;                     // 0..31
    const int g   = n0 + row;
    const int c0  = (t & 7) * 16;               // float offset in row
    float4 f0, f1, f2, f3;
    if (g < nNodes) {
      const float* xr = x + (size_t)g * FIN + c0;
      f0 = *(const float4*)(xr + 0);  f1 = *(const float4*)(xr + 4);
      f2 = *(const float4*)(xr + 8);  f3 = *(const float4*)(xr + 12);
    } else {
      f0 = f1 = f2 = f3 = make_float4(0.f, 0.f, 0.f, 0.f);
    }
    unsigned short u[16];
    u[0]=f2bf(f0.x); u[1]=f2bf(f0.y); u[2]=f2bf(f0.z); u[3]=f2bf(f0.w);
    u[4]=f2bf(f1.x); u[5]=f2bf(f1.y); u[6]=f2bf(f1.z); u[7]=f2bf(f1.w);
    u[8]=f2bf(f2.x); u[9]=f2bf(f2.y); u[10]=f2bf(f2.z); u[11]=f2bf(f2.w);
    u[12]=f2bf(f3.x); u[13]=f2bf(f3.y); u[14]=f2bf(f3.z); u[15]=f2bf(f3.w);
    const int sw = (row & 7) << 4;
    char* base = (char*)As + row * 256;
    *(uint4*)(base + (((t & 7) * 32)      ^ sw)) = *(const uint4*)(u + 0);
    *(uint4*)(base + (((t & 7) * 32 + 16) ^ sw)) = *(const uint4*)(u + 8);
  }

  const int w    = t >> 6;                      // wave == head
  const int l    = t & 63;
  const int lrow = l & 15;

  // ---- B fragments directly from W (L2-resident after first blocks) ----
  frag_ab bfr[4][4];                            // [nf][ks]
  #pragma unroll
  for (int nf = 0; nf < 4; ++nf) {
    const int colW = w * 64 + nf * 16 + lrow;
    #pragma unroll
    for (int ks = 0; ks < 4; ++ks) {
      const int k0 = ks * 32 + (l >> 4) * 8;
      frag_ab f;
      #pragma unroll
      for (int j = 0; j < 8; ++j)
        f[j] = (short)f2bf(W[(size_t)(k0 + j) * HIDDEN + colW]);
      bfr[nf][ks] = f;
    }
  }
  __syncthreads();

  frag_ab afr[2][4];                            // [mf][ks]
  const int lsw = (lrow & 7) << 4;
  #pragma unroll
  for (int mf = 0; mf < 2; ++mf)
    #pragma unroll
    for (int ks = 0; ks < 4; ++ks) {
      int byte = (mf * 16 + lrow) * 256 + ((ks * 64 + (l >> 4) * 16) ^ lsw);
      afr[mf][ks] = *(const frag_ab*)((const char*)As + byte);
    }

  frag_cd acc[2][4];
  #pragma unroll
  for (int mf = 0; mf < 2; ++mf)
    #pragma unroll
    for (int nf = 0; nf < 4; ++nf)
      acc[mf][nf] = (frag_cd){0.f, 0.f, 0.f, 0.f};
  #pragma unroll
  for (int ks = 0; ks < 4; ++ks)
    #pragma unroll
    for (int mf = 0; mf < 2; ++mf)
      #pragma unroll
      for (int nf = 0; nf < 4; ++nf)
        acc[mf][nf] = __builtin_amdgcn_mfma_f32_16x16x32_bf16(
            afr[mf][ks], bfr[nf][ks], acc[mf][nf], 0, 0, 0);

  float asw[4], adw[4];
  #pragma unroll
  for (int nf = 0; nf < 4; ++nf) {
    asw[nf] = att_s[w * 64 + nf * 16 + lrow];
    adw[nf] = att_d[w * 64 + nf * 16 + lrow];
  }

  #pragma unroll
  for (int mf = 0; mf < 2; ++mf) {
    #pragma unroll
    for (int r = 0; r < 4; ++r) {
      const int rowg = n0 + mf * 16 + (l >> 4) * 4 + r;
      if (rowg < nNodes) {
        #pragma unroll
        for (int nf = 0; nf < 4; ++nf)
          h16[(size_t)rowg * HIDDEN + w * 64 + nf * 16 + lrow] = f2bf(acc[mf][nf][r]);
      }
      float ss = 0.f, sd = 0.f;
      #pragma unroll
      for (int nf = 0; nf < 4; ++nf) {
        ss = fmaf(acc[mf][nf][r], asw[nf], ss);
        sd = fmaf(acc[mf][nf][r], adw[nf], sd);
      }
      #pragma unroll
      for (int off2 = 1; off2 <= 8; off2 <<= 1) {
        ss += __shfl_xor(ss, off2, 64);
        sd += __shfl_xor(sd, off2, 64);
      }
      if (lrow == 0 && rowg < nNodes) {
        a_src[rowg * HEADS + w] = ss;
        a_dst[rowg * HEADS + w] = sd;
      }
    }
  }
}

// ================= phase device functions (shared by mega + fallback) =================

__device__ void phase_scan(const int* __restrict__ cnt, int* __restrict__ offs,
                           int* __restrict__ cursor, int n, int total,
                           int sb, int blk, int G, int* iscr)
{
  const int t = threadIdx.x;
  for (int vb = blk; vb < sb; vb += G) {
    int partial = 0;
    for (int j = t; j < vb * 256; j += 256) partial += cnt[j];
    #pragma unroll
    for (int off2 = 32; off2; off2 >>= 1) partial += __shfl_xor(partial, off2, 64);
    if ((t & 63) == 0) iscr[t >> 6] = partial;
    __syncthreads();
    const int base = iscr[0] + iscr[1] + iscr[2] + iscr[3] + vb * 256; // +1/node self loop
    const int i = vb * 256 + t;
    const int v = (i < n) ? cnt[i] + 1 : 0;
    int sc = v;
    #pragma unroll
    for (int d2 = 1; d2 < 64; d2 <<= 1) {
      int u = __shfl_up(sc, d2, 64);
      if ((t & 63) >= d2) sc += u;
    }
    if ((t & 63) == 63) iscr[4 + (t >> 6)] = sc;
    __syncthreads();
    int wb = 0;
    for (int w2 = 0; w2 < (t >> 6); ++w2) wb += iscr[4 + w2];
    const int excl = base + wb + sc - v;
    if (i < n) { offs[i] = excl; cursor[i] = excl; }
    if (i == 0) offs[n] = total;
    __syncthreads();
  }
}

__device__ void phase_scatter(const int* __restrict__ ei, int* __restrict__ cursor,
                              int* __restrict__ ssrc, int E, int N, int blk, int G)
{
  const int tot = E + N;
  for (int e = blk * 256 + (int)threadIdx.x; e < tot; e += G * 256) {
    int s, d;
    if (e < E) { s = ei[e]; d = ei[E + e]; }
    else       { s = e - E; d = s; }        // self loop
    int pos = atomicAdd(&cursor[d], 1);
    ssrc[pos] = s;
  }
}

__device__ void phase_agg(const unsigned short* __restrict__ h16, const int* __restrict__ offs,
                          const int* __restrict__ ssrc, const float* __restrict__ a_src,
                          const float* __restrict__ a_dst, const float* __restrict__ bias,
                          unsigned short* __restrict__ outn, int N, int blk, int G)
{
  const int lane = threadIdx.x & 63;
  const int head = lane >> 4;
  const int col  = lane << 2;
  const float4 bv = *(const float4*)&bias[col];

  for (int wid = blk * WPB + ((int)threadIdx.x >> 6); wid < N; wid += G * WPB) {
    const int beg = offs[wid], end = offs[wid + 1];
    const float ad = a_dst[wid * 4 + head];

    float4 acc = make_float4(0.f, 0.f, 0.f, 0.f);
    float den = 0.f;
    int k = beg;

    for (; k + 8 <= end; k += 8) {
      int s0 = ssrc[k + 0], s1 = ssrc[k + 1], s2 = ssrc[k + 2], s3 = ssrc[k + 3];
      int s4 = ssrc[k + 4], s5 = ssrc[k + 5], s6 = ssrc[k + 6], s7 = ssrc[k + 7];
      float e0 = a_src[s0 * 4 + head], e1 = a_src[s1 * 4 + head];
      float e2 = a_src[s2 * 4 + head], e3 = a_src[s3 * 4 + head];
      float e4 = a_src[s4 * 4 + head], e5 = a_src[s5 * 4 + head];
      float e6 = a_src[s6 * 4 + head], e7 = a_src[s7 * 4 + head];
      ushort4 h0 = *(const ushort4*)(h16 + (size_t)s0 * HIDDEN + col);
      ushort4 h1 = *(const ushort4*)(h16 + (size_t)s1 * HIDDEN + col);
      ushort4 h2 = *(const ushort4*)(h16 + (size_t)s2 * HIDDEN + col);
      ushort4 h3 = *(const ushort4*)(h16 + (size_t)s3 * HIDDEN + col);
      ushort4 h4 = *(const ushort4*)(h16 + (size_t)s4 * HIDDEN + col);
      ushort4 h5 = *(const ushort4*)(h16 + (size_t)s5 * HIDDEN + col);
      ushort4 h6 = *(const ushort4*)(h16 + (size_t)s6 * HIDDEN + col);
      ushort4 h7 = *(const ushort4*)(h16 + (size_t)s7 * HIDDEN + col);
      float w0, w1, w2, w3, w4, w5, w6, w7;
      e0 += ad; e0 = e0 > 0.f ? e0 : 0.2f * e0; w0 = __expf(e0);
      e1 += ad; e1 = e1 > 0.f ? e1 : 0.2f * e1; w1 = __expf(e1);
      e2 += ad; e2 = e2 > 0.f ? e2 : 0.2f * e2; w2 = __expf(e2);
      e3 += ad; e3 = e3 > 0.f ? e3 : 0.2f * e3; w3 = __expf(e3);
      e4 += ad; e4 = e4 > 0.f ? e4 : 0.2f * e4; w4 = __expf(e4);
      e5 += ad; e5 = e5 > 0.f ? e5 : 0.2f * e5; w5 = __expf(e5);
      e6 += ad; e6 = e6 > 0.f ? e6 : 0.2f * e6; w6 = __expf(e6);
      e7 += ad; e7 = e7 > 0.f ? e7 : 0.2f * e7; w7 = __expf(e7);
      den += ((w0 + w1) + (w2 + w3)) + ((w4 + w5) + (w6 + w7));
      acc.x = fmaf(bf2f(h0.x), w0, acc.x); acc.y = fmaf(bf2f(h0.y), w0, acc.y);
      acc.z = fmaf(bf2f(h0.z), w0, acc.z); acc.w = fmaf(bf2f(h0.w), w0, acc.w);
      acc.x = fmaf(bf2f(h1.x), w1, acc.x); acc.y = fmaf(bf2f(h1.y), w1, acc.y);
      acc.z = fmaf(bf2f(h1.z), w1, acc.z); acc.w = fmaf(bf2f(h1.w), w1, acc.w);
      acc.x = fmaf(bf2f(h2.x), w2, acc.x); acc.y = fmaf(bf2f(h2.y), w2, acc.y);
      acc.z = fmaf(bf2f(h2.z), w2, acc.z); acc.w = fmaf(bf2f(h2.w), w2, acc.w);
      acc.x = fmaf(bf2f(h3.x), w3, acc.x); acc.y = fmaf(bf2f(h3.y), w3, acc.y);
      acc.z = fmaf(bf2f(h3.z), w3, acc.z); acc.w = fmaf(bf2f(h3.w), w3, acc.w);
      acc.x = fmaf(bf2f(h4.x), w4, acc.x); acc.y = fmaf(bf2f(h4.y), w4, acc.y);
      acc.z = fmaf(bf2f(h4.z), w4, acc.z); acc.w = fmaf(bf2f(h4.w), w4, acc.w);
      acc.x = fmaf(bf2f(h5.x), w5, acc.x); acc.y = fmaf(bf2f(h5.y), w5, acc.y);
      acc.z = fmaf(bf2f(h5.z), w5, acc.z); acc.w = fmaf(bf2f(h5.w), w5, acc.w);
      acc.x = fmaf(bf2f(h6.x), w6, acc.x); acc.y = fmaf(bf2f(h6.y), w6, acc.y);
      acc.z = fmaf(bf2f(h6.z), w6, acc.z); acc.w = fmaf(bf2f(h6.w), w6, acc.w);
      acc.x = fmaf(bf2f(h7.x), w7, acc.x); acc.y = fmaf(bf2f(h7.y), w7, acc.y);
      acc.z = fmaf(bf2f(h7.z), w7, acc.z); acc.w = fmaf(bf2f(h7.w), w7, acc.w);
    }
    for (; k < end; ++k) {
      int s = ssrc[k];
      float v = a_src[s * 4 + head] + ad;
      v = v > 0.f ? v : 0.2f * v;
      float w = __expf(v);
      ushort4 hv = *(const ushort4*)(h16 + (size_t)s * HIDDEN + col);
      den += w;
      acc.x = fmaf(bf2f(hv.x), w, acc.x); acc.y = fmaf(bf2f(hv.y), w, acc.y);
      acc.z = fmaf(bf2f(hv.z), w, acc.z); acc.w = fmaf(bf2f(hv.w), w, acc.w);
    }

    const float inv = 1.f / den;          // den > 0 guaranteed by self loop
    float4 o;
    o.x = fmaf(acc.x, inv, bv.x); o.x = o.x > 0.f ? o.x : expm1f(o.x);
    o.y = fmaf(acc.y, inv, bv.y); o.y = o.y > 0.f ? o.y : expm1f(o.y);
    o.z = fmaf(acc.z, inv, bv.z); o.z = o.z > 0.f ? o.z : expm1f(o.z);
    o.w = fmaf(acc.w, inv, bv.w); o.w = o.w > 0.f ? o.w : expm1f(o.w);

    ushort4 ov;
    ov.x = f2bf(o.x); ov.y = f2bf(o.y); ov.z = f2bf(o.z); ov.w = f2bf(o.w);
    *(ushort4*)(outn + (size_t)wid * HIDDEN + col) = ov;
  }
}

__device__ void phase_pool(const unsigned short* __restrict__ outn, const int* __restrict__ batch,
                           float* __restrict__ pooled, float* __restrict__ cntg,
                           int N, int nch, int blk, int G)
{
  const int t = threadIdx.x;
  for (int c = blk; c < nch; c += G) {
    const int n0 = c * PCHUNK;
    const int n1 = (n0 + PCHUNK < N) ? n0 + PCHUNK : N;
    int cur = batch[n0];
    float run = 0.f;
    int runlen = 0;
    int n = n0;
    for (; n + 4 <= n1; n += 4) {
      unsigned short r0 = outn[(size_t)(n + 0) * HIDDEN + t];
      unsigned short r1 = outn[(size_t)(n + 1) * HIDDEN + t];
      unsigned short r2 = outn[(size_t)(n + 2) * HIDDEN + t];
      unsigned short r3 = outn[(size_t)(n + 3) * HIDDEN + t];
      int g0 = batch[n + 0], g3 = batch[n + 3];
      if (g0 == cur && g3 == cur) {
        run += (bf2f(r0) + bf2f(r1)) + (bf2f(r2) + bf2f(r3));
        runlen += 4;
      } else {
        unsigned short rr[4] = {r0, r1, r2, r3};
        #pragma unroll
        for (int j = 0; j < 4; ++j) {
          int g = batch[n + j];
          if (g != cur) {
            atomicAdd(&pooled[cur * HIDDEN + t], run);
            if (t == 0) atomicAdd(&cntg[cur], (float)runlen);
            run = 0.f; runlen = 0; cur = g;
          }
          run += bf2f(rr[j]); runlen++;
        }
      }
    }
    for (; n < n1; ++n) {
      int g = batch[n];
      if (g != cur) {
        atomicAdd(&pooled[cur * HIDDEN + t], run);
        if (t == 0) atomicAdd(&cntg[cur], (float)runlen);
        run = 0.f; runlen = 0; cur = g;
      }
      run += bf2f(outn[(size_t)n * HIDDEN + t]); runlen++;
    }
    atomicAdd(&pooled[cur * HIDDEN + t], run);
    if (t == 0) atomicAdd(&cntg[cur], (float)runlen);
  }
}

__device__ void phase_fc(const float* __restrict__ pooled, const float* __restrict__ cntg,
                         const float* __restrict__ fc_w, const float* __restrict__ fc_b,
                         float* __restrict__ out, int blk, int G, float* fscr)
{
  const int t = threadIdx.x;
  for (int g = blk; g < NGRAPH; g += G) {
    float v = pooled[g * HIDDEN + t] * fc_w[t];
    #pragma unroll
    for (int off2 = 32; off2; off2 >>= 1) v += __shfl_xor(v, off2, 64);
    if ((t & 63) == 0) fscr[t >> 6] = v;
    __syncthreads();
    if (t == 0) {
      // atomic load: cntg written by atomics this kernel (avoid stale scalar cache)
      float c = __hip_atomic_load(&cntg[g], __ATOMIC_RELAXED, __HIP_MEMORY_SCOPE_AGENT);
      out[g] = (fscr[0] + fscr[1] + fscr[2] + fscr[3]) / fmaxf(c, 1.0f) + fc_b[0];
    }
    __syncthreads();
  }
}

// ================= cooperative mega-kernel =================
struct MegaArgs {
  const int* cnt; int* offs; int* cursor; const int* ei; int* ssrc;
  const unsigned short* h16; const float* a_src; const float* a_dst; const float* bias;
  unsigned short* outn; const int* batch; float* pooled; float* cntg;
  const float* fc_w; const float* fc_b; float* out;
  int N, E, sb, nch;
};

__global__ __launch_bounds__(256, 4) void k_mega(MegaArgs A)
{
  __shared__ int   iscr[8];
  __shared__ float fscr[4];
  const int blk = blockIdx.x;
  const int G   = gridDim.x;
  cg::grid_group grid = cg::this_grid();

  phase_scan(A.cnt, A.offs, A.cursor, A.N, A.E + A.N, A.sb, blk, G, iscr);
  __threadfence(); grid.sync(); __threadfence();
  phase_scatter(A.ei, A.cursor, A.ssrc, A.E, A.N, blk, G);
  __threadfence(); grid.sync(); __threadfence();
  phase_agg(A.h16, A.offs, A.ssrc, A.a_src, A.a_dst, A.bias, A.outn, A.N, blk, G);
  __threadfence(); grid.sync(); __threadfence();
  phase_pool(A.outn, A.batch, A.pooled, A.cntg, A.N, A.nch, blk, G);
  __threadfence(); grid.sync(); __threadfence();
  phase_fc(A.pooled, A.cntg, A.fc_w, A.fc_b, A.out, blk, G, fscr);
}

// ================= fallback thin kernels (if cooperative launch unavailable) =================
__global__ __launch_bounds__(256) void k_scanF(const int* cnt, int* offs, int* cursor,
                                               int n, int total, int sb)
{ __shared__ int iscr[8]; phase_scan(cnt, offs, cursor, n, total, sb, blockIdx.x, gridDim.x, iscr); }

__global__ __launch_bounds__(256) void k_scatF(const int* ei, int* cursor, int* ssrc, int E, int N)
{ phase_scatter(ei, cursor, ssrc, E, N, blockIdx.x, gridDim.x); }

__global__ __launch_bounds__(256) void k_aggF(const unsigned short* h16, const int* offs,
                                              const int* ssrc, const float* a_src,
                                              const float* a_dst, const float* bias,
                                              unsigned short* outn, int N)
{ phase_agg(h16, offs, ssrc, a_src, a_dst, bias, outn, N, blockIdx.x, gridDim.x); }

__global__ __launch_bounds__(256) void k_poolF(const unsigned short* outn, const int* batch,
                                               float* pooled, float* cntg, int N, int nch)
{ phase_pool(outn, batch, pooled, cntg, N, nch, blockIdx.x, gridDim.x); }

__global__ __launch_bounds__(256) void k_fcF(const float* pooled, const float* cntg,
                                             const float* fc_w, const float* fc_b, float* out)
{ __shared__ float fscr[4]; phase_fc(pooled, cntg, fc_w, fc_b, out, blockIdx.x, gridDim.x, fscr); }

// ================= host =================
extern "C" void kernel_launch(void* const* d_in, const int* in_sizes, int n_in,
                              void* d_out, int out_size, void* d_ws, size_t ws_size,
                              hipStream_t stream)
{
  const float* x     = (const float*)d_in[0];
  const int*   ei    = (const int*)  d_in[1];   // [2,E] flat: [0..E)=src, [E..2E)=dst
  /* d_in[2] edge_attr: unused by reference */
  const int*   batch = (const int*)  d_in[3];
  const float* W     = (const float*)d_in[4];
  const float* att_s = (const float*)d_in[5];
  const float* att_d = (const float*)d_in[6];
  const float* bias  = (const float*)d_in[7];
  const float* fc_w  = (const float*)d_in[8];
  const float* fc_b  = (const float*)d_in[9];
  float* out = (float*)d_out;

  const int N   = in_sizes[0] / FIN;
  const int E   = in_sizes[1] / 2;
  const int TOT = E + N;

  char* p = (char*)d_ws;
  size_t o = 0;
  auto alloc = [&](size_t bytes) -> void* {
    void* r = p + o;
    o = (o + bytes + 255) & ~(size_t)255;
    return r;
  };
  // zero-init region first: one memset covers [count | pooled | cntg]
  int*   count  = (int*)  alloc((size_t)N * sizeof(int));
  float* pooled = (float*)alloc((size_t)NGRAPH * HIDDEN * sizeof(float));
  float* cntg   = (float*)alloc((size_t)NGRAPH * sizeof(float));
  size_t zeroBytes = o;
  unsigned short* h16 = (unsigned short*)alloc((size_t)N * HIDDEN * sizeof(unsigned short));
  float* a_src  = (float*)alloc((size_t)N * 4 * sizeof(float));
  float* a_dst  = (float*)alloc((size_t)N * 4 * sizeof(float));
  int*   offs   = (int*)  alloc((size_t)(N + 1) * sizeof(int));
  int*   cursor = (int*)  alloc((size_t)N * sizeof(int));
  int*   ssrc   = (int*)  alloc((size_t)TOT * sizeof(int));
  unsigned short* outn = (unsigned short*)alloc((size_t)N * HIDDEN * sizeof(unsigned short));
  (void)n_in; (void)out_size; (void)ws_size;

  (void)hipMemsetAsync(d_ws, 0, zeroBytes, stream);

  const int gemmBlocks = (N + 31) / 32;
  hipLaunchKernelGGL(k_gemmhist, dim3(gemmBlocks + HISTB), dim3(256), 0, stream,
                     x, W, att_s, att_d, h16, a_src, a_dst, ei, count, N, E, gemmBlocks);

  const int sb  = (N + 255) / 256;
  const int nch = (N + PCHUNK - 1) / PCHUNK;
  MegaArgs ma;
  ma.cnt = count; ma.offs = offs; ma.cursor = cursor; ma.ei = ei; ma.ssrc = ssrc;
  ma.h16 = h16; ma.a_src = a_src; ma.a_dst = a_dst; ma.bias = bias;
  ma.outn = outn; ma.batch = batch; ma.pooled = pooled; ma.cntg = cntg;
  ma.fc_w = fc_w; ma.fc_b = fc_b; ma.out = out;
  ma.N = N; ma.E = E; ma.sb = sb; ma.nch = nch;

  int maxB = 0;
  hipError_t oe = hipOccupancyMaxActiveBlocksPerMultiprocessor(&maxB, k_mega, 256, 0);
  if (oe != hipSuccess || maxB <= 0) maxB = 2;
  int G = maxB * 256;                 // 256 CUs on MI355X
  if (G > 1024) G = 1024;

  void* margs[] = { (void*)&ma };
  hipError_t ce = hipLaunchCooperativeKernel(k_mega, dim3(G), dim3(256), margs, 0, stream);
  if (ce != hipSuccess) {
    // fallback: same phases as separate dispatches
    hipLaunchKernelGGL(k_scanF, dim3(sb), dim3(256), 0, stream, count, offs, cursor, N, TOT, sb);
    hipLaunchKernelGGL(k_scatF, dim3((TOT + 255) / 256), dim3(256), 0, stream, ei, cursor, ssrc, E, N);
    hipLaunchKernelGGL(k_aggF, dim3((N + WPB - 1) / WPB), dim3(256), 0, stream,
                       h16, offs, ssrc, a_src, a_dst, bias, outn, N);
    hipLaunchKernelGGL(k_poolF, dim3(nch), dim3(256), 0, stream, outn, batch, pooled, cntg, N, nch);
    hipLaunchKernelGGL(k_fcF, dim3(NGRAPH), dim3(256), 0, stream, pooled, cntg, fc_w, fc_b, out);
  }
}